// Round 8
// baseline (341.027 us; speedup 1.0000x reference)
//
#include <hip/hip_runtime.h>
#include <hip/hip_bf16.h>
#include <cmath>

typedef __bf16 bf16;
typedef __bf16 bf16x8 __attribute__((ext_vector_type(8)));
typedef __bf16 bf16x4 __attribute__((ext_vector_type(4)));
typedef __bf16 bf16x2 __attribute__((ext_vector_type(2)));
typedef float  f32x4  __attribute__((ext_vector_type(4)));
typedef float  f32x16 __attribute__((ext_vector_type(16)));
typedef int    i32x4  __attribute__((ext_vector_type(4)));

#define B_   2
#define T_   2048
#define D_   1024
#define H_   16
#define DH_  64
#define BT_  (B_ * T_)     // 4096
#define DFF_ (4 * D_)      // 4096

#define GLDS(gp, lp) __builtin_amdgcn_global_load_lds( \
    (const __attribute__((address_space(1))) void*)(gp), \
    (__attribute__((address_space(3))) void*)(lp), 16, 0, 0)
#define VMCNT(n) asm volatile("s_waitcnt vmcnt(" #n ")" ::: "memory")

// ---------------- fp32 -> bf16 convert, 4 elems/thread ----------------
__global__ void cvt_f32_bf16(const float* __restrict__ src, bf16* __restrict__ dst, int n) {
    int i = (blockIdx.x * blockDim.x + threadIdx.x) * 4;
    if (i >= n) return;
    float4 v = *(const float4*)(src + i);
    bf16x4 o;
    o[0] = (bf16)v.x; o[1] = (bf16)v.y; o[2] = (bf16)v.z; o[3] = (bf16)v.w;
    *(bf16x4*)(dst + i) = o;
}

__device__ __forceinline__ float gelu_f(float v) {
    return 0.5f * v * (1.0f + erff(v * 0.70710678118654752f));
}

__device__ __forceinline__ int pkbf(float a, float b) {
    bf16x2 v; v[0] = (bf16)a; v[1] = (bf16)b;
    return __builtin_bit_cast(int, v);
}

// ---------------- V transpose: vrow [B][T][1024] -> vt [B][1024][T] ----------------
__global__ __launch_bounds__(256) void transpose_v(
    const bf16* __restrict__ vrow, bf16* __restrict__ vt)
{
    __shared__ bf16 tile[64][72];
    const int tb = blockIdx.x;
    const int eb = blockIdx.y;
    const int b  = blockIdx.z;
    const int c  = threadIdx.x;

    const bf16* src = vrow + ((long)b * T_ + tb * 64) * 1024 + eb * 64;
    #pragma unroll
    for (int j = 0; j < 2; j++) {
        int ch = c + j * 256;
        int r = ch >> 3, s = ch & 7;
        *(bf16x8*)&tile[r][s * 8] = *(const bf16x8*)&src[(long)r * 1024 + s * 8];
    }
    __syncthreads();
    bf16* dst = vt + ((long)b * 1024 + eb * 64) * 2048 + tb * 64;
    #pragma unroll
    for (int j = 0; j < 2; j++) {
        int ch = c + j * 256;
        int r = ch >> 3, s = ch & 7;
        bf16x8 o;
        #pragma unroll
        for (int k = 0; k < 8; k++) o[k] = tile[s * 8 + k][r];
        *(bf16x8*)&dst[(long)r * 2048 + s * 8] = o;
    }
}

// ============ 256x256 8-phase GEMM (m201-template port), BK=64 ============
// C[M,N] = A[M,K]*Bt[N,K]^T. 512 thr = 8 waves (2M x 4N); per-wave C 128x64.
// LDS: 2 slots x 2 units x [128 rows][8 slots x 8 bf16] per operand = 128KB.
// A-unit u rows-in-tile: {wm*128 + u*64 + 0..63}; B-unit v: {wn*64 + v*32 + 0..31}.
// Slot swizzle: stage writes linear chunk, source k-seg = slot ^ (lrow&7);
// read slot = (kt*4+g) ^ (cc&7). Phase q=(u,v): 12 ds_read + stage + vmcnt + bar +
// 16 MFMA + bar. Stages: q0 -> (t+1) unit1 pair; q2 -> (t+2) A-u0; q3 -> (t+2) B-u0.
// vmcnt: q0: t<NT-1 ? 8 : 0; q3: t<NT-2 ? 8 : (t==NT-2 ? 4 : 0).
#define AOFF(s,u) ((((s)*2+(u))*128)*64)
template <int EPI>   // 1: gelu(acc+bias) bf16; 3: QKV split qk/vrow
__global__ __launch_bounds__(512, 2) void gemm8p(
    const bf16* __restrict__ A, const bf16* __restrict__ Bt,
    void* __restrict__ outp, void* __restrict__ outp2,
    const float* __restrict__ bias, int M, int N, int K)
{
    __shared__ __align__(16) bf16 As[2 * 2 * 128 * 64];
    __shared__ __align__(16) bf16 Bs[2 * 2 * 128 * 64];
    const int tid  = threadIdx.x;
    const int lane = tid & 63, w = tid >> 6;
    const int wm = w >> 2, wn = w & 3;
    const int g = lane >> 4, cc = lane & 15;
    const int key = cc & 7;
    const int m0 = blockIdx.y * 256, n0 = blockIdx.x * 256;
    const int NT = K >> 6;

    f32x4 acc[8][4] = {};

    // staging: unit = 1024 chunks of 16B; thread -> chunks tid, tid+512 (linear LDS dest)
    const int c0 = tid, c1 = tid + 512;
    const int l0 = c0 >> 3, k0 = (((c0 & 7) ^ (l0 & 7)) << 3);
    const int l1 = c1 >> 3, k1 = (((c1 & 7) ^ (l1 & 7)) << 3);
    const int ar0 = ((l0 >> 6) << 7) + (l0 & 63);
    const int ar1 = ((l1 >> 6) << 7) + (l1 & 63);
    const int br0 = ((l0 >> 5) << 6) + (l0 & 31);
    const int br1 = ((l1 >> 5) << 6) + (l1 & 31);

    auto stageA = [&](int t, int u) {
        const int s = t & 1; const long kb = (long)t << 6;
        GLDS(A + (long)(m0 + ar0 + u * 64) * K + kb + k0, &As[AOFF(s, u) + c0 * 8]);
        GLDS(A + (long)(m0 + ar1 + u * 64) * K + kb + k1, &As[AOFF(s, u) + c1 * 8]);
    };
    auto stageB = [&](int t, int v) {
        const int s = t & 1; const long kb = (long)t << 6;
        GLDS(Bt + (long)(n0 + br0 + v * 32) * K + kb + k0, &Bs[AOFF(s, v) + c0 * 8]);
        GLDS(Bt + (long)(n0 + br1 + v * 32) * K + kb + k1, &Bs[AOFF(s, v) + c1 * 8]);
    };

    // prologue: tile0 fully (8 loads) + tile1 h0 units (4 loads); wait tile0
    stageA(0, 0); stageB(0, 0); stageA(0, 1); stageB(0, 1);
    stageA(1, 0); stageB(1, 0);
    VMCNT(4);
    __builtin_amdgcn_s_barrier();

    for (int t = 0; t < NT; ++t) {
        const int s = t & 1;
        #pragma unroll
        for (int q = 0; q < 4; ++q) {
            const int u = q >> 1, v = q & 1;
            // ---- 12 ds_read_b128 for quadrant (u,v), full K=64 ----
            bf16x8 af[4][2], bfr[2][2];
            #pragma unroll
            for (int mi = 0; mi < 4; mi++)
                #pragma unroll
                for (int kt = 0; kt < 2; kt++) {
                    int l  = wm * 64 + mi * 16 + cc;
                    int sl = ((kt << 2) | g) ^ key;
                    af[mi][kt] = *(const bf16x8*)&As[AOFF(s, u) + l * 64 + sl * 8];
                }
            #pragma unroll
            for (int ni = 0; ni < 2; ni++)
                #pragma unroll
                for (int kt = 0; kt < 2; kt++) {
                    int l  = wn * 32 + ni * 16 + cc;
                    int sl = ((kt << 2) | g) ^ key;
                    bfr[ni][kt] = *(const bf16x8*)&Bs[AOFF(s, v) + l * 64 + sl * 8];
                }
            // ---- stage per schedule (regions freed by preceding barriers) ----
            if (q == 0)      { if (t + 1 < NT) { stageA(t + 1, 1); stageB(t + 1, 1); } }
            else if (q == 2) { if (t + 2 < NT) stageA(t + 2, 0); }
            else if (q == 3) { if (t + 2 < NT) stageB(t + 2, 0); }
            // ---- counted vmcnt (ledger-derived; exact at tail) ----
            if (q == 0) { if (t < NT - 1) { VMCNT(8); } else { VMCNT(0); } }
            if (q == 3) {
                if (t < NT - 2)       { VMCNT(8); }
                else if (t == NT - 2) { VMCNT(4); }
                else                  { VMCNT(0); }
            }
            __builtin_amdgcn_s_barrier();
            __builtin_amdgcn_s_setprio(1);
            #pragma unroll
            for (int kt = 0; kt < 2; kt++)
                #pragma unroll
                for (int mi = 0; mi < 4; mi++)
                    #pragma unroll
                    for (int ni = 0; ni < 2; ni++)
                        acc[u * 4 + mi][v * 2 + ni] = __builtin_amdgcn_mfma_f32_16x16x32_bf16(
                            af[mi][kt], bfr[ni][kt], acc[u * 4 + mi][v * 2 + ni], 0, 0, 0);
            __builtin_amdgcn_s_setprio(0);
            __builtin_amdgcn_s_barrier();
        }
    }

    // epilogue: row = m0+wm*128+u*64+mi*16+g*4+r ; col = n0+wn*64+v*32+ni*16+cc
    #pragma unroll
    for (int am = 0; am < 8; am++) {
        #pragma unroll
        for (int an = 0; an < 4; an++) {
            const int uu = am >> 2, mi = am & 3, vv = an >> 1, ni = an & 1;
            #pragma unroll
            for (int r = 0; r < 4; r++) {
                int grow = m0 + wm * 128 + uu * 64 + mi * 16 + g * 4 + r;
                int gcol = n0 + wn * 64 + vv * 32 + ni * 16 + cc;
                float vv_ = acc[am][an][r];
                if constexpr (EPI == 3) {
                    if (n0 >= 2048)
                        ((bf16*)outp2)[(long)grow * 1024 + (gcol - 2048)] = (bf16)vv_;
                    else
                        ((bf16*)outp)[(long)grow * 2048 + gcol] = (bf16)vv_;
                } else {
                    vv_ += bias[gcol];
                    ((bf16*)outp)[(long)grow * N + gcol] = (bf16)gelu_f(vv_);
                }
            }
        }
    }
}

// ---------------- m97-style 128x128 GEMM for FFN2 (K=4096 regime, proven) ----------
__global__ __launch_bounds__(256) void gemm128_ffn2(
    const bf16* __restrict__ A, const bf16* __restrict__ Bt,
    float* __restrict__ outp, const float* __restrict__ bias,
    const float* __restrict__ resid, int M, int N, int K)
{
    __shared__ __align__(16) bf16 As[128 * 32];
    __shared__ __align__(16) bf16 Bs[128 * 32];
    const int tid  = threadIdx.x;
    const int lane = tid & 63;
    const int w    = tid >> 6;
    const int wr   = w >> 1, wc = w & 1;
    const int g    = lane >> 4, cc = lane & 15;
    const int m0   = blockIdx.y * 128, n0 = blockIdx.x * 128;

    f32x4 acc[4][4] = {};

    const int c0 = tid, c1 = tid + 256;
    const bf16* gA0 = A  + (long)(m0 + (c0 >> 2)) * K + ((c0 & 3) << 3);
    const bf16* gA1 = A  + (long)(m0 + (c1 >> 2)) * K + ((c1 & 3) << 3);
    const bf16* gB0 = Bt + (long)(n0 + (c0 >> 2)) * K + ((c0 & 3) << 3);
    const bf16* gB1 = Bt + (long)(n0 + (c1 >> 2)) * K + ((c1 & 3) << 3);
    bf16* lA0 = As + c0 * 8;
    bf16* lA1 = As + c1 * 8;
    bf16* lB0 = Bs + c0 * 8;
    bf16* lB1 = Bs + c1 * 8;

    for (int k0 = 0; k0 < K; k0 += 32) {
        GLDS(gA0 + k0, lA0);
        GLDS(gA1 + k0, lA1);
        GLDS(gB0 + k0, lB0);
        GLDS(gB1 + k0, lB1);
        __syncthreads();

        bf16x8 af[4], bfr[4];
        #pragma unroll
        for (int mi = 0; mi < 4; mi++)
            af[mi] = *(const bf16x8*)&As[(wr * 64 + mi * 16 + cc) * 32 + g * 8];
        #pragma unroll
        for (int ni = 0; ni < 4; ni++)
            bfr[ni] = *(const bf16x8*)&Bs[(wc * 64 + ni * 16 + cc) * 32 + g * 8];
        #pragma unroll
        for (int mi = 0; mi < 4; mi++)
            #pragma unroll
            for (int ni = 0; ni < 4; ni++)
                acc[mi][ni] = __builtin_amdgcn_mfma_f32_16x16x32_bf16(af[mi], bfr[ni], acc[mi][ni], 0, 0, 0);
        __syncthreads();
    }

    #pragma unroll
    for (int mi = 0; mi < 4; mi++)
        #pragma unroll
        for (int ni = 0; ni < 4; ni++)
            #pragma unroll
            for (int r = 0; r < 4; r++) {
                int grow = m0 + wr * 64 + mi * 16 + g * 4 + r;
                int gcol = n0 + wc * 64 + ni * 16 + cc;
                outp[(long)grow * N + gcol] =
                    acc[mi][ni][r] + bias[gcol] + resid[(long)grow * N + gcol];
            }
}

// ---------------- flash attention v5: swapped-QK 32x32 MFMA, in-register softmax ---
__global__ __launch_bounds__(256) void attn_kernel(
    const bf16* __restrict__ qk, const bf16* __restrict__ vt,
    const float* __restrict__ x, bf16* __restrict__ hout)
{
    __shared__ __align__(16) bf16 Ks[2][64 * 64];
    __shared__ __align__(16) bf16 Vs[2][64 * 64];
    const int tid  = threadIdx.x;
    const int lane = tid & 63, w = tid >> 6;
    const int l31 = lane & 31, hi = lane >> 5;
    const int qb = gridDim.x - 1 - blockIdx.x;
    const int hh = blockIdx.y, b = blockIdx.z;
    const int qbase = qb * 128;
    const int qw0 = qbase + w * 32;
    const int qg  = qw0 + l31;

    const bf16* qkb   = qk + (long)b * T_ * 2048;
    const bf16* kbase = qkb + 1024 + hh * 64;
    const bf16* vbase = vt + ((long)b * 1024 + hh * 64) * 2048;

    bf16x8 qf[4];
    {
        const bf16* qrow = qkb + (long)qg * 2048 + hh * 64;
        #pragma unroll
        for (int ks = 0; ks < 4; ks++) {
            bf16x8 v = *(const bf16x8*)&qrow[ks * 16 + hi * 8];
            #pragma unroll
            for (int j = 0; j < 8; j++) v[j] = (bf16)((float)v[j] * 0.125f);
            qf[ks] = v;
        }
    }

    float m_run = -INFINITY, l_run = 0.f;
    f32x16 o0 = {}, o1 = {};

    const int ntiles = (qbase >> 6) + 2;
    const int my_end = ((qw0 + 31) >> 6) + 1;

    auto stage = [&](int i) {
        const int buf = i & 1;
        const long kv0 = (long)i << 6;
        #pragma unroll
        for (int j = 0; j < 2; j++) {
            int c = tid + j * 256;
            int r = c >> 3, s = c & 7;
            int seg = (s ^ (r & 7)) << 3;
            GLDS(kbase + (kv0 + r) * 2048 + seg, &Ks[buf][c * 8]);
            GLDS(vbase + (long)r * 2048 + kv0 + seg, &Vs[buf][c * 8]);
        }
    };

    stage(0);
    __syncthreads();

    for (int i = 0; i < ntiles; ++i) {
        const int buf = i & 1;
        const int kv0 = i << 6;
        if (i + 1 < ntiles) stage(i + 1);

        if (i < my_end) {
            f32x16 s0 = {}, s1 = {};
            const int xk = l31 & 7;
            #pragma unroll
            for (int ks = 0; ks < 4; ks++) {
                int slot = ((2 * ks + hi) ^ xk) << 3;
                bf16x8 kf0 = *(const bf16x8*)&Ks[buf][l31 * 64 + slot];
                bf16x8 kf1 = *(const bf16x8*)&Ks[buf][(32 + l31) * 64 + slot];
                s0 = __builtin_amdgcn_mfma_f32_32x32x16_bf16(kf0, qf[ks], s0, 0, 0, 0);
                s1 = __builtin_amdgcn_mfma_f32_32x32x16_bf16(kf1, qf[ks], s1, 0, 0, 0);
            }

            if (kv0 + 64 > qw0) {
                #pragma unroll
                for (int r = 0; r < 16; r++) {
                    int kvr = kv0 + (r & 3) + 8 * (r >> 2) + 4 * hi;
                    if (kvr > qg)      s0[r] = -INFINITY;
                    if (kvr + 32 > qg) s1[r] = -INFINITY;
                }
            }

            float pm = s0[0];
            #pragma unroll
            for (int r = 1; r < 16; r++) pm = fmaxf(pm, s0[r]);
            #pragma unroll
            for (int r = 0; r < 16; r++) pm = fmaxf(pm, s1[r]);
            pm = fmaxf(pm, __shfl_xor(pm, 32));

            if (!__all(pm <= m_run + 8.f)) {
                float mn = fmaxf(m_run, pm);
                float al = __expf(m_run - mn);
                m_run = mn;
                l_run *= al;
                #pragma unroll
                for (int r = 0; r < 16; r++) {
                    float av = __shfl(al, (r & 3) + 8 * (r >> 2) + 4 * hi);
                    o0[r] *= av; o1[r] *= av;
                }
            }

            float rs = 0.f;
            #pragma unroll
            for (int r = 0; r < 16; r++) { float p = __expf(s0[r] - m_run); s0[r] = p; rs += p; }
            #pragma unroll
            for (int r = 0; r < 16; r++) { float p = __expf(s1[r] - m_run); s1[r] = p; rs += p; }
            rs += __shfl_xor(rs, 32);
            l_run += rs;

            i32x4 pw[4];
            {
                int d0[4], d1[4];
                #pragma unroll
                for (int m = 0; m < 4; m++) {
                    d0[m] = pkbf(s0[4 * m],     s0[4 * m + 1]);
                    d1[m] = pkbf(s0[4 * m + 2], s0[4 * m + 3]);
                }
                #pragma unroll
                for (int k2 = 0; k2 < 2; k2++) {
                    int r0 = __shfl_xor(d0[2 * k2 + 1 - hi], 32);
                    int r1 = __shfl_xor(d1[2 * k2 + 1 - hi], 32);
                    i32x4 t;
                    t[0] = hi ? r0 : d0[2 * k2];
                    t[1] = hi ? r1 : d1[2 * k2];
                    t[2] = hi ? d0[2 * k2 + 1] : r0;
                    t[3] = hi ? d1[2 * k2 + 1] : r1;
                    pw[k2] = t;
                }
            }
            {
                int d0[4], d1[4];
                #pragma unroll
                for (int m = 0; m < 4; m++) {
                    d0[m] = pkbf(s1[4 * m],     s1[4 * m + 1]);
                    d1[m] = pkbf(s1[4 * m + 2], s1[4 * m + 3]);
                }
                #pragma unroll
                for (int k2 = 0; k2 < 2; k2++) {
                    int r0 = __shfl_xor(d0[2 * k2 + 1 - hi], 32);
                    int r1 = __shfl_xor(d1[2 * k2 + 1 - hi], 32);
                    i32x4 t;
                    t[0] = hi ? r0 : d0[2 * k2];
                    t[1] = hi ? r1 : d1[2 * k2];
                    t[2] = hi ? d0[2 * k2 + 1] : r0;
                    t[3] = hi ? d1[2 * k2 + 1] : r1;
                    pw[2 + k2] = t;
                }
            }

            #pragma unroll
            for (int sl = 0; sl < 4; sl++) {
                bf16x8 pa = __builtin_bit_cast(bf16x8, pw[sl]);
                int slot = ((2 * sl + hi) ^ xk) << 3;
                bf16x8 vf0 = *(const bf16x8*)&Vs[buf][l31 * 64 + slot];
                bf16x8 vf1 = *(const bf16x8*)&Vs[buf][(32 + l31) * 64 + slot];
                o0 = __builtin_amdgcn_mfma_f32_32x32x16_bf16(pa, vf0, o0, 0, 0, 0);
                o1 = __builtin_amdgcn_mfma_f32_32x32x16_bf16(pa, vf1, o1, 0, 0, 0);
            }
        }
        __syncthreads();
    }

    #pragma unroll
    for (int r = 0; r < 16; r++) {
        int qr = (r & 3) + 8 * (r >> 2) + 4 * hi;
        float lr = __shfl(l_run, qr);
        int grow = qbase + w * 32 + qr;
        long base = ((long)b * T_ + grow) * 1024 + hh * 64 + l31;
        hout[base]      = (bf16)(x[base]      + o0[r] / lr);
        hout[base + 32] = (bf16)(x[base + 32] + o1[r] / lr);
    }
}

// ---------------- launch ----------------
extern "C" void kernel_launch(void* const* d_in, const int* in_sizes, int n_in,
                              void* d_out, int out_size, void* d_ws, size_t ws_size,
                              hipStream_t stream) {
    const float* x  = (const float*)d_in[0];
    const float* wq = (const float*)d_in[2];
    const float* wk = (const float*)d_in[3];
    const float* wv = (const float*)d_in[4];
    const float* w1 = (const float*)d_in[5];
    const float* b1 = (const float*)d_in[6];
    const float* w2 = (const float*)d_in[7];
    const float* b2 = (const float*)d_in[8];
    float* out = (float*)d_out;

    char* ws = (char*)d_ws;
    bf16* xb   = (bf16*)(ws);                  // [4096,1024]   8 MB
    bf16* wall = (bf16*)(ws + (8L  << 20));    // [3072,1024]   6 MB
    bf16* w1b  = (bf16*)(ws + (14L << 20));    // [4096,1024]   8 MB
    bf16* w2b  = (bf16*)(ws + (22L << 20));    // [1024,4096]   8 MB
    bf16* qkb  = (bf16*)(ws + (30L << 20));    // [4096,2048]  16 MB
    bf16* vtb  = (bf16*)(ws + (46L << 20));    // [2,1024,2048] 8 MB
    bf16* hbuf = (bf16*)(ws + (54L << 20));    // [4096,1024]   8 MB (also vrow scratch)
    bf16* abuf = (bf16*)(ws + (62L << 20));    // [4096,4096]  32 MB
    bf16* vrow = hbuf;  // consumed by transpose_v BEFORE attn writes hbuf

    auto cvt = [&](const float* s, bf16* d, int n) {
        cvt_f32_bf16<<<(n / 4 + 255) / 256, 256, 0, stream>>>(s, d, n);
    };
    cvt(x,  xb,              BT_ * D_);
    cvt(wq, wall,            D_ * D_);
    cvt(wk, wall + D_ * D_,  D_ * D_);
    cvt(wv, wall + 2 * D_ * D_, D_ * D_);
    cvt(w1, w1b, DFF_ * D_);
    cvt(w2, w2b, D_ * DFF_);

    // QKV projection (8-phase 256^2): -> qk [4096,2048] + vrow [4096,1024]
    gemm8p<3><<<dim3(3 * D_ / 256, BT_ / 256), 512, 0, stream>>>(
        xb, wall, qkb, vrow, nullptr, BT_, 3 * D_, D_);

    // V transpose: vrow -> vt [2][1024][2048]
    transpose_v<<<dim3(T_ / 64, D_ / 64, B_), 256, 0, stream>>>(vrow, vtb);

    // attention + residual: hbuf = x + attn_out
    attn_kernel<<<dim3(T_ / 128, H_, B_), 256, 0, stream>>>(qkb, vtb, x, hbuf);

    // FFN1 (8-phase 256^2): gelu(h @ w1^T + b1) -> abuf [4096,4096] bf16
    gemm8p<1><<<dim3(DFF_ / 256, BT_ / 256), 512, 0, stream>>>(
        hbuf, w1b, abuf, nullptr, b1, BT_, DFF_, D_);

    // FFN2 + bias + residual x -> out fp32 [4096,1024]
    gemm128_ffn2<<<dim3(D_ / 128, BT_ / 128), 256, 0, stream>>>(
        abuf, w2b, out, b2, x, BT_, D_, DFF_);
}

// Round 9
// 275.219 us; speedup vs baseline: 1.2391x; 1.2391x over previous
//
#include <hip/hip_runtime.h>
#include <hip/hip_bf16.h>
#include <cmath>

typedef __bf16 bf16;
typedef __bf16 bf16x8 __attribute__((ext_vector_type(8)));
typedef __bf16 bf16x4 __attribute__((ext_vector_type(4)));
typedef __bf16 bf16x2 __attribute__((ext_vector_type(2)));
typedef float  f32x4  __attribute__((ext_vector_type(4)));
typedef float  f32x16 __attribute__((ext_vector_type(16)));
typedef int    i32x4  __attribute__((ext_vector_type(4)));

#define B_   2
#define T_   2048
#define D_   1024
#define H_   16
#define DH_  64
#define BT_  (B_ * T_)     // 4096
#define DFF_ (4 * D_)      // 4096

#define GLDS(gp, lp) __builtin_amdgcn_global_load_lds( \
    (const __attribute__((address_space(1))) void*)(gp), \
    (__attribute__((address_space(3))) void*)(lp), 16, 0, 0)
#define VMCNT(n) asm volatile("s_waitcnt vmcnt(" #n ")" ::: "memory")

// ---------------- fp32 -> bf16 convert, 4 elems/thread ----------------
__global__ void cvt_f32_bf16(const float* __restrict__ src, bf16* __restrict__ dst, int n) {
    int i = (blockIdx.x * blockDim.x + threadIdx.x) * 4;
    if (i >= n) return;
    float4 v = *(const float4*)(src + i);
    bf16x4 o;
    o[0] = (bf16)v.x; o[1] = (bf16)v.y; o[2] = (bf16)v.z; o[3] = (bf16)v.w;
    *(bf16x4*)(dst + i) = o;
}

__device__ __forceinline__ float gelu_f(float v) {
    return 0.5f * v * (1.0f + erff(v * 0.70710678118654752f));
}

__device__ __forceinline__ int pkbf(float a, float b) {
    bf16x2 v; v[0] = (bf16)a; v[1] = (bf16)b;
    return __builtin_bit_cast(int, v);
}

// ---------------- V transpose: vrow [B][T][1024] -> vt [B][1024][T] ----------------
__global__ __launch_bounds__(256) void transpose_v(
    const bf16* __restrict__ vrow, bf16* __restrict__ vt)
{
    __shared__ bf16 tile[64][72];
    const int tb = blockIdx.x;
    const int eb = blockIdx.y;
    const int b  = blockIdx.z;
    const int c  = threadIdx.x;

    const bf16* src = vrow + ((long)b * T_ + tb * 64) * 1024 + eb * 64;
    #pragma unroll
    for (int j = 0; j < 2; j++) {
        int ch = c + j * 256;
        int r = ch >> 3, s = ch & 7;
        *(bf16x8*)&tile[r][s * 8] = *(const bf16x8*)&src[(long)r * 1024 + s * 8];
    }
    __syncthreads();
    bf16* dst = vt + ((long)b * 1024 + eb * 64) * 2048 + tb * 64;
    #pragma unroll
    for (int j = 0; j < 2; j++) {
        int ch = c + j * 256;
        int r = ch >> 3, s = ch & 7;
        bf16x8 o;
        #pragma unroll
        for (int k = 0; k < 8; k++) o[k] = tile[s * 8 + k][r];
        *(bf16x8*)&dst[(long)r * 2048 + s * 8] = o;
    }
}

// ---------------- GEMM: C[M,N] = A[M,K] * Bt[N,K]^T ---------------------------
// 128x128 tile, BK=32, ring-2 LDS double-buffer, T3-minimum 2-phase schedule:
//   stage(t+1) issued BEFORE compute(t); single vmcnt(0)+barrier per tile.
// EPI 1: bf16 out = gelu(acc + bias); EPI 2: f32 out = acc + bias + resid
// EPI 3: QKV split: col < 2048 -> qk rowmajor [M][2048]; col >= 2048 -> vrow [M][1024]
template <int EPI>
__global__ __launch_bounds__(256) void gemm_bt(
    const bf16* __restrict__ A, const bf16* __restrict__ Bt,
    void* __restrict__ outp, void* __restrict__ outp2, const float* __restrict__ bias,
    const float* __restrict__ resid, int M, int N, int K)
{
    __shared__ __align__(16) bf16 As[2][128 * 32];
    __shared__ __align__(16) bf16 Bs[2][128 * 32];
    const int tid  = threadIdx.x;
    const int lane = tid & 63;
    const int w    = tid >> 6;
    const int wr   = w >> 1, wc = w & 1;
    const int g    = lane >> 4, cc = lane & 15;
    const int m0   = blockIdx.y * 128, n0 = blockIdx.x * 128;
    const int NT   = K >> 5;

    f32x4 acc[4][4] = {};

    const int c0 = tid, c1 = tid + 256;
    const bf16* gA0 = A  + (long)(m0 + (c0 >> 2)) * K + ((c0 & 3) << 3);
    const bf16* gA1 = A  + (long)(m0 + (c1 >> 2)) * K + ((c1 & 3) << 3);
    const bf16* gB0 = Bt + (long)(n0 + (c0 >> 2)) * K + ((c0 & 3) << 3);
    const bf16* gB1 = Bt + (long)(n0 + (c1 >> 2)) * K + ((c1 & 3) << 3);

    auto stage = [&](int t) {
        const int buf = t & 1;
        const long k0 = (long)t << 5;
        GLDS(gA0 + k0, &As[buf][c0 * 8]);
        GLDS(gA1 + k0, &As[buf][c1 * 8]);
        GLDS(gB0 + k0, &Bs[buf][c0 * 8]);
        GLDS(gB1 + k0, &Bs[buf][c1 * 8]);
    };

    // prologue: tile 0 staged and landed before first compute
    stage(0);
    VMCNT(0);
    __builtin_amdgcn_s_barrier();

    for (int t = 0; t < NT; ++t) {
        const bf16* Ab = As[t & 1];
        const bf16* Bb = Bs[t & 1];
        if (t + 1 < NT) stage(t + 1);   // into other buffer; latency hides under compute

        bf16x8 af[4], bfr[4];
        #pragma unroll
        for (int mi = 0; mi < 4; mi++)
            af[mi] = *(const bf16x8*)&Ab[(wr * 64 + mi * 16 + cc) * 32 + g * 8];
        #pragma unroll
        for (int ni = 0; ni < 4; ni++)
            bfr[ni] = *(const bf16x8*)&Bb[(wc * 64 + ni * 16 + cc) * 32 + g * 8];
        #pragma unroll
        for (int mi = 0; mi < 4; mi++)
            #pragma unroll
            for (int ni = 0; ni < 4; ni++)
                acc[mi][ni] = __builtin_amdgcn_mfma_f32_16x16x32_bf16(af[mi], bfr[ni], acc[mi][ni], 0, 0, 0);

        VMCNT(0);                        // stage(t+1) landed (issued ~full tile ago)
        __builtin_amdgcn_s_barrier();    // all waves done reading buf[t&1] + writes visible
    }

    #pragma unroll
    for (int mi = 0; mi < 4; mi++) {
        #pragma unroll
        for (int ni = 0; ni < 4; ni++) {
            #pragma unroll
            for (int r = 0; r < 4; r++) {
                int grow = m0 + wr * 64 + mi * 16 + g * 4 + r;
                int gcol = n0 + wc * 64 + ni * 16 + cc;
                float v = acc[mi][ni][r];
                if constexpr (EPI == 3) {
                    if (gcol < 2048)
                        ((bf16*)outp)[(long)grow * 2048 + gcol] = (bf16)v;
                    else
                        ((bf16*)outp2)[(long)grow * 1024 + (gcol - 2048)] = (bf16)v;
                } else if constexpr (EPI == 1) {
                    v += bias[gcol];
                    ((bf16*)outp)[(long)grow * N + gcol] = (bf16)gelu_f(v);
                } else {
                    v += bias[gcol] + resid[(long)grow * N + gcol];
                    ((float*)outp)[(long)grow * N + gcol] = v;
                }
            }
        }
    }
}

// ---------------- flash attention v5: swapped-QK 32x32 MFMA, in-register softmax ---
__global__ __launch_bounds__(256) void attn_kernel(
    const bf16* __restrict__ qk, const bf16* __restrict__ vt,
    const float* __restrict__ x, bf16* __restrict__ hout)
{
    __shared__ __align__(16) bf16 Ks[2][64 * 64];
    __shared__ __align__(16) bf16 Vs[2][64 * 64];
    const int tid  = threadIdx.x;
    const int lane = tid & 63, w = tid >> 6;
    const int l31 = lane & 31, hi = lane >> 5;
    const int qb = gridDim.x - 1 - blockIdx.x;
    const int hh = blockIdx.y, b = blockIdx.z;
    const int qbase = qb * 128;
    const int qw0 = qbase + w * 32;
    const int qg  = qw0 + l31;

    const bf16* qkb   = qk + (long)b * T_ * 2048;
    const bf16* kbase = qkb + 1024 + hh * 64;
    const bf16* vbase = vt + ((long)b * 1024 + hh * 64) * 2048;

    bf16x8 qf[4];
    {
        const bf16* qrow = qkb + (long)qg * 2048 + hh * 64;
        #pragma unroll
        for (int ks = 0; ks < 4; ks++) {
            bf16x8 v = *(const bf16x8*)&qrow[ks * 16 + hi * 8];
            #pragma unroll
            for (int j = 0; j < 8; j++) v[j] = (bf16)((float)v[j] * 0.125f);
            qf[ks] = v;
        }
    }

    float m_run = -INFINITY, l_run = 0.f;
    f32x16 o0 = {}, o1 = {};

    const int ntiles = (qbase >> 6) + 2;
    const int my_end = ((qw0 + 31) >> 6) + 1;

    auto stage = [&](int i) {
        const int buf = i & 1;
        const long kv0 = (long)i << 6;
        #pragma unroll
        for (int j = 0; j < 2; j++) {
            int c = tid + j * 256;
            int r = c >> 3, s = c & 7;
            int seg = (s ^ (r & 7)) << 3;
            GLDS(kbase + (kv0 + r) * 2048 + seg, &Ks[buf][c * 8]);
            GLDS(vbase + (long)r * 2048 + kv0 + seg, &Vs[buf][c * 8]);
        }
    };

    stage(0);
    __syncthreads();

    for (int i = 0; i < ntiles; ++i) {
        const int buf = i & 1;
        const int kv0 = i << 6;
        if (i + 1 < ntiles) stage(i + 1);

        if (i < my_end) {
            f32x16 s0 = {}, s1 = {};
            const int xk = l31 & 7;
            #pragma unroll
            for (int ks = 0; ks < 4; ks++) {
                int slot = ((2 * ks + hi) ^ xk) << 3;
                bf16x8 kf0 = *(const bf16x8*)&Ks[buf][l31 * 64 + slot];
                bf16x8 kf1 = *(const bf16x8*)&Ks[buf][(32 + l31) * 64 + slot];
                s0 = __builtin_amdgcn_mfma_f32_32x32x16_bf16(kf0, qf[ks], s0, 0, 0, 0);
                s1 = __builtin_amdgcn_mfma_f32_32x32x16_bf16(kf1, qf[ks], s1, 0, 0, 0);
            }

            if (kv0 + 64 > qw0) {
                #pragma unroll
                for (int r = 0; r < 16; r++) {
                    int kvr = kv0 + (r & 3) + 8 * (r >> 2) + 4 * hi;
                    if (kvr > qg)      s0[r] = -INFINITY;
                    if (kvr + 32 > qg) s1[r] = -INFINITY;
                }
            }

            float pm = s0[0];
            #pragma unroll
            for (int r = 1; r < 16; r++) pm = fmaxf(pm, s0[r]);
            #pragma unroll
            for (int r = 0; r < 16; r++) pm = fmaxf(pm, s1[r]);
            pm = fmaxf(pm, __shfl_xor(pm, 32));

            if (!__all(pm <= m_run + 8.f)) {
                float mn = fmaxf(m_run, pm);
                float al = __expf(m_run - mn);
                m_run = mn;
                l_run *= al;
                #pragma unroll
                for (int r = 0; r < 16; r++) {
                    float av = __shfl(al, (r & 3) + 8 * (r >> 2) + 4 * hi);
                    o0[r] *= av; o1[r] *= av;
                }
            }

            float rs = 0.f;
            #pragma unroll
            for (int r = 0; r < 16; r++) { float p = __expf(s0[r] - m_run); s0[r] = p; rs += p; }
            #pragma unroll
            for (int r = 0; r < 16; r++) { float p = __expf(s1[r] - m_run); s1[r] = p; rs += p; }
            rs += __shfl_xor(rs, 32);
            l_run += rs;

            i32x4 pw[4];
            {
                int d0[4], d1[4];
                #pragma unroll
                for (int m = 0; m < 4; m++) {
                    d0[m] = pkbf(s0[4 * m],     s0[4 * m + 1]);
                    d1[m] = pkbf(s0[4 * m + 2], s0[4 * m + 3]);
                }
                #pragma unroll
                for (int k2 = 0; k2 < 2; k2++) {
                    int r0 = __shfl_xor(d0[2 * k2 + 1 - hi], 32);
                    int r1 = __shfl_xor(d1[2 * k2 + 1 - hi], 32);
                    i32x4 t;
                    t[0] = hi ? r0 : d0[2 * k2];
                    t[1] = hi ? r1 : d1[2 * k2];
                    t[2] = hi ? d0[2 * k2 + 1] : r0;
                    t[3] = hi ? d1[2 * k2 + 1] : r1;
                    pw[k2] = t;
                }
            }
            {
                int d0[4], d1[4];
                #pragma unroll
                for (int m = 0; m < 4; m++) {
                    d0[m] = pkbf(s1[4 * m],     s1[4 * m + 1]);
                    d1[m] = pkbf(s1[4 * m + 2], s1[4 * m + 3]);
                }
                #pragma unroll
                for (int k2 = 0; k2 < 2; k2++) {
                    int r0 = __shfl_xor(d0[2 * k2 + 1 - hi], 32);
                    int r1 = __shfl_xor(d1[2 * k2 + 1 - hi], 32);
                    i32x4 t;
                    t[0] = hi ? r0 : d0[2 * k2];
                    t[1] = hi ? r1 : d1[2 * k2];
                    t[2] = hi ? d0[2 * k2 + 1] : r0;
                    t[3] = hi ? d1[2 * k2 + 1] : r1;
                    pw[2 + k2] = t;
                }
            }

            #pragma unroll
            for (int sl = 0; sl < 4; sl++) {
                bf16x8 pa = __builtin_bit_cast(bf16x8, pw[sl]);
                int slot = ((2 * sl + hi) ^ xk) << 3;
                bf16x8 vf0 = *(const bf16x8*)&Vs[buf][l31 * 64 + slot];
                bf16x8 vf1 = *(const bf16x8*)&Vs[buf][(32 + l31) * 64 + slot];
                o0 = __builtin_amdgcn_mfma_f32_32x32x16_bf16(pa, vf0, o0, 0, 0, 0);
                o1 = __builtin_amdgcn_mfma_f32_32x32x16_bf16(pa, vf1, o1, 0, 0, 0);
            }
        }
        __syncthreads();
    }

    #pragma unroll
    for (int r = 0; r < 16; r++) {
        int qr = (r & 3) + 8 * (r >> 2) + 4 * hi;
        float lr = __shfl(l_run, qr);
        int grow = qbase + w * 32 + qr;
        long base = ((long)b * T_ + grow) * 1024 + hh * 64 + l31;
        hout[base]      = (bf16)(x[base]      + o0[r] / lr);
        hout[base + 32] = (bf16)(x[base + 32] + o1[r] / lr);
    }
}

// ---------------- launch ----------------
extern "C" void kernel_launch(void* const* d_in, const int* in_sizes, int n_in,
                              void* d_out, int out_size, void* d_ws, size_t ws_size,
                              hipStream_t stream) {
    const float* x  = (const float*)d_in[0];
    const float* wq = (const float*)d_in[2];
    const float* wk = (const float*)d_in[3];
    const float* wv = (const float*)d_in[4];
    const float* w1 = (const float*)d_in[5];
    const float* b1 = (const float*)d_in[6];
    const float* w2 = (const float*)d_in[7];
    const float* b2 = (const float*)d_in[8];
    float* out = (float*)d_out;

    char* ws = (char*)d_ws;
    bf16* xb   = (bf16*)(ws);                  // [4096,1024]   8 MB
    bf16* wall = (bf16*)(ws + (8L  << 20));    // [3072,1024]   6 MB
    bf16* w1b  = (bf16*)(ws + (14L << 20));    // [4096,1024]   8 MB
    bf16* w2b  = (bf16*)(ws + (22L << 20));    // [1024,4096]   8 MB
    bf16* qkb  = (bf16*)(ws + (30L << 20));    // [4096,2048]  16 MB
    bf16* vtb  = (bf16*)(ws + (46L << 20));    // [2,1024,2048] 8 MB
    bf16* hbuf = (bf16*)(ws + (54L << 20));    // [4096,1024]   8 MB (also vrow scratch)
    bf16* abuf = (bf16*)(ws + (62L << 20));    // [4096,4096]  32 MB
    bf16* vrow = hbuf;  // consumed by transpose_v BEFORE attn writes hbuf

    auto cvt = [&](const float* s, bf16* d, int n) {
        cvt_f32_bf16<<<(n / 4 + 255) / 256, 256, 0, stream>>>(s, d, n);
    };
    cvt(x,  xb,              BT_ * D_);
    cvt(wq, wall,            D_ * D_);
    cvt(wk, wall + D_ * D_,  D_ * D_);
    cvt(wv, wall + 2 * D_ * D_, D_ * D_);
    cvt(w1, w1b, DFF_ * D_);
    cvt(w2, w2b, D_ * DFF_);

    // QKV projection: -> qk [4096,2048] + vrow [4096,1024]
    gemm_bt<3><<<dim3(3 * D_ / 128, BT_ / 128), 256, 0, stream>>>(
        xb, wall, qkb, vrow, nullptr, nullptr, BT_, 3 * D_, D_);

    // V transpose: vrow -> vt [2][1024][2048]
    transpose_v<<<dim3(T_ / 64, D_ / 64, B_), 256, 0, stream>>>(vrow, vtb);

    // attention + residual: hbuf = x + attn_out
    attn_kernel<<<dim3(T_ / 128, H_, B_), 256, 0, stream>>>(qkb, vtb, x, hbuf);

    // FFN1: gelu(h @ w1^T + b1) -> abuf [4096,4096] bf16
    gemm_bt<1><<<dim3(DFF_ / 128, BT_ / 128), 256, 0, stream>>>(
        hbuf, w1b, abuf, nullptr, b1, nullptr, BT_, DFF_, D_);

    // FFN2 + bias + residual x -> out fp32 [4096,1024]
    gemm_bt<2><<<dim3(D_ / 128, BT_ / 128), 256, 0, stream>>>(
        abuf, w2b, out, nullptr, b2, x, BT_, D_, DFF_);
}